// Round 2
// baseline (482.312 us; speedup 1.0000x reference)
//
#include <hip/hip_runtime.h>
#include <math.h>

// CumulativeLayerNorm, single-pass fused kernel (decoupled look-back).
// inputs [B,K,H] f32, gamma/beta [1,H] f32.
// out[b,k,h] = gamma[h]*(x[b,k,h]-mean[b,k])*rsqrt(var[b,k]+1e-8)+beta[h],
// mean/var over prefix inputs[b,:k+1,:].
//
// Each block owns TILE=16 consecutive frames of one batch chain:
//   1) load tile -> LDS (float4), per-frame sum/sumsq via wave shuffle
//   2) thread0: fp64 intra-tile inclusive scan; publish tile aggregate
//   3) wave0: windowed (64-wide) look-back over predecessor tiles -> exclusive
//      prefix; publish inclusive prefix (device-scope atomics, arrival-order
//      virtual block ids => no dispatch-order assumption)
//   4) normalize from LDS, write out (float4)
// Traffic: 131 MB read + 131 MB write + ~5 MB descriptors -> ~40 us @ 7 TB/s.

#define HDIM 512
#define F4H (HDIM / 4)        // 128 float4 per frame
#define TILE 16               // frames per block (32 KB LDS)
#define BATCHES 8

typedef unsigned long long u64;

__device__ __forceinline__ double wave_sum_d(double v) {
    #pragma unroll
    for (int off = 32; off >= 1; off >>= 1) v += __shfl_xor(v, off);
    return v;
}

__global__ __launch_bounds__(256) void cln_fused(
    const float* __restrict__ in, const float* __restrict__ gamma,
    const float* __restrict__ beta, float* __restrict__ out,
    int K, int tilesPerBatch,
    u64* __restrict__ aggS, u64* __restrict__ aggQ,
    u64* __restrict__ preS, u64* __restrict__ preQ,
    unsigned int* __restrict__ flags, unsigned int* __restrict__ counter)
{
    __shared__ float xs[TILE * HDIM];          // 32 KB staged tile
    __shared__ float fsum[TILE], fsq[TILE];    // per-frame sums
    __shared__ double csum[TILE], csq[TILE];   // intra-tile inclusive scan
    __shared__ double exS_s, exQ_s;            // exclusive prefix for tile
    __shared__ unsigned int vid_s;

    const int t = threadIdx.x;
    const int lane = t & 63;
    const int wid = t >> 6;

    if (t == 0) vid_s = atomicAdd(counter, 1u);   // arrival-order virtual id
    __syncthreads();
    const unsigned int vid = vid_s;
    const int b    = vid % BATCHES;               // chain (batch)
    const int tile = vid / BATCHES;               // position within chain
    const int k0   = tile * TILE;                 // first within-batch frame
    const int me   = b * tilesPerBatch + tile;

    // gamma/beta for this lane's columns (issue early, used in phase 4)
    const float4 g0 = ((const float4*)gamma)[lane];
    const float4 g1 = ((const float4*)gamma)[lane + 64];
    const float4 be0 = ((const float4*)beta)[lane];
    const float4 be1 = ((const float4*)beta)[lane + 64];

    // ---- phase 1: load tile -> LDS, per-frame sum/sumsq ----
    #pragma unroll
    for (int i = 0; i < TILE / 4; ++i) {
        const int fi = wid * 4 + i;               // frame within tile
        const int k = k0 + fi;
        if (k < K) {
            const float4* p = (const float4*)in + ((size_t)b * K + k) * F4H;
            float4 a = p[lane];
            float4 c = p[lane + 64];
            ((float4*)xs)[fi * F4H + lane] = a;
            ((float4*)xs)[fi * F4H + 64 + lane] = c;
            float s = (a.x + a.y) + (a.z + a.w) + (c.x + c.y) + (c.z + c.w);
            float q = (a.x * a.x + a.y * a.y) + (a.z * a.z + a.w * a.w)
                    + (c.x * c.x + c.y * c.y) + (c.z * c.z + c.w * c.w);
            #pragma unroll
            for (int off = 32; off >= 1; off >>= 1) {
                s += __shfl_xor(s, off);
                q += __shfl_xor(q, off);
            }
            if (lane == 0) { fsum[fi] = s; fsq[fi] = q; }
        }
    }
    __syncthreads();

    // ---- phase 2: intra-tile fp64 scan + publish aggregate ----
    if (t == 0) {
        double s = 0.0, q = 0.0;
        for (int fi = 0; fi < TILE; ++fi) {
            if (k0 + fi < K) { s += (double)fsum[fi]; q += (double)fsq[fi]; }
            csum[fi] = s; csq[fi] = q;
        }
        __hip_atomic_store(&aggS[me], __double_as_longlong(s),
                           __ATOMIC_RELAXED, __HIP_MEMORY_SCOPE_AGENT);
        __hip_atomic_store(&aggQ[me], __double_as_longlong(q),
                           __ATOMIC_RELAXED, __HIP_MEMORY_SCOPE_AGENT);
        if (tile == 0) {
            exS_s = 0.0; exQ_s = 0.0;
            __hip_atomic_store(&preS[me], __double_as_longlong(s),
                               __ATOMIC_RELAXED, __HIP_MEMORY_SCOPE_AGENT);
            __hip_atomic_store(&preQ[me], __double_as_longlong(q),
                               __ATOMIC_RELAXED, __HIP_MEMORY_SCOPE_AGENT);
            __threadfence();
            __hip_atomic_store(&flags[me], 2u,
                               __ATOMIC_RELEASE, __HIP_MEMORY_SCOPE_AGENT);
        } else {
            __threadfence();
            __hip_atomic_store(&flags[me], 1u,
                               __ATOMIC_RELEASE, __HIP_MEMORY_SCOPE_AGENT);
        }
    }

    // ---- phase 3: windowed look-back (wave 0 only) ----
    if (tile > 0 && wid == 0) {
        double es = 0.0, eq = 0.0;
        int base = tile - 1;
        for (;;) {
            const int j = base - lane;
            const bool valid = (j >= 0);
            const int idx = valid ? (b * tilesPerBatch + j) : 0;
            unsigned int f;
            do {  // poll until every valid predecessor in window published
                f = valid ? __hip_atomic_load(&flags[idx], __ATOMIC_ACQUIRE,
                                              __HIP_MEMORY_SCOPE_AGENT)
                          : 1u;
            } while (__ballot(f == 0u) != 0ull);

            const unsigned long long pmask = __ballot(valid && f == 2u);
            double as = 0.0, aq = 0.0;
            if (pmask != 0ull) {
                const int p = __ffsll((long long)pmask) - 1;  // closest prefix
                if (lane < p) {
                    as = __longlong_as_double(__hip_atomic_load(&aggS[idx],
                            __ATOMIC_RELAXED, __HIP_MEMORY_SCOPE_AGENT));
                    aq = __longlong_as_double(__hip_atomic_load(&aggQ[idx],
                            __ATOMIC_RELAXED, __HIP_MEMORY_SCOPE_AGENT));
                } else if (lane == p) {
                    as = __longlong_as_double(__hip_atomic_load(&preS[idx],
                            __ATOMIC_RELAXED, __HIP_MEMORY_SCOPE_AGENT));
                    aq = __longlong_as_double(__hip_atomic_load(&preQ[idx],
                            __ATOMIC_RELAXED, __HIP_MEMORY_SCOPE_AGENT));
                }
                es += wave_sum_d(as);
                eq += wave_sum_d(aq);
                break;
            } else {
                if (valid) {
                    as = __longlong_as_double(__hip_atomic_load(&aggS[idx],
                            __ATOMIC_RELAXED, __HIP_MEMORY_SCOPE_AGENT));
                    aq = __longlong_as_double(__hip_atomic_load(&aggQ[idx],
                            __ATOMIC_RELAXED, __HIP_MEMORY_SCOPE_AGENT));
                }
                es += wave_sum_d(as);
                eq += wave_sum_d(aq);
                base -= 64;
                if (base < 0) break;   // unreachable: tile 0 always flag==2
            }
        }
        if (lane == 0) {
            exS_s = es; exQ_s = eq;
            __hip_atomic_store(&preS[me],
                __double_as_longlong(es + csum[TILE - 1]),
                __ATOMIC_RELAXED, __HIP_MEMORY_SCOPE_AGENT);
            __hip_atomic_store(&preQ[me],
                __double_as_longlong(eq + csq[TILE - 1]),
                __ATOMIC_RELAXED, __HIP_MEMORY_SCOPE_AGENT);
            __threadfence();
            __hip_atomic_store(&flags[me], 2u,
                               __ATOMIC_RELEASE, __HIP_MEMORY_SCOPE_AGENT);
        }
    }
    __syncthreads();

    // ---- phase 4: normalize from LDS, write out ----
    const double es = exS_s, eq = exQ_s;
    #pragma unroll
    for (int i = 0; i < TILE / 4; ++i) {
        const int fi = wid * 4 + i;
        const int k = k0 + fi;
        if (k < K) {
            const double cnt = (double)(k + 1) * (double)HDIM;
            const double mean = (es + csum[fi]) / cnt;
            const double var = (eq + csq[fi]) / cnt - mean * mean;
            const float m = (float)mean;
            const float r = (float)(1.0 / sqrt(var + 1e-8));
            float4 a = ((float4*)xs)[fi * F4H + lane];
            float4 c = ((float4*)xs)[fi * F4H + 64 + lane];
            float4 o0, o1;
            o0.x = g0.x * ((a.x - m) * r) + be0.x;
            o0.y = g0.y * ((a.y - m) * r) + be0.y;
            o0.z = g0.z * ((a.z - m) * r) + be0.z;
            o0.w = g0.w * ((a.w - m) * r) + be0.w;
            o1.x = g1.x * ((c.x - m) * r) + be1.x;
            o1.y = g1.y * ((c.y - m) * r) + be1.y;
            o1.z = g1.z * ((c.z - m) * r) + be1.z;
            o1.w = g1.w * ((c.w - m) * r) + be1.w;
            float4* q = (float4*)out + ((size_t)b * K + k) * F4H;
            q[lane] = o0;
            q[lane + 64] = o1;
        }
    }
}

extern "C" void kernel_launch(void* const* d_in, const int* in_sizes, int n_in,
                              void* d_out, int out_size, void* d_ws, size_t ws_size,
                              hipStream_t stream)
{
    const float* in    = (const float*)d_in[0];
    const float* gamma = (const float*)d_in[1];
    const float* beta  = (const float*)d_in[2];
    float* out = (float*)d_out;

    const int H = in_sizes[1];          // 512
    const int BK = in_sizes[0] / H;     // B*K
    const int B = BATCHES;              // fixed by setup_inputs()
    const int K = BK / B;               // 8000
    const int tilesPerBatch = (K + TILE - 1) / TILE;   // 500
    const int NT = B * tilesPerBatch;                   // 4000
    (void)H; (void)n_in; (void)out_size; (void)ws_size;

    // ws layout: aggS|aggQ|preS|preQ (u64 each, NT) then flags (u32, NT) + counter
    u64* aggS = (u64*)d_ws;
    u64* aggQ = aggS + NT;
    u64* preS = aggQ + NT;
    u64* preQ = preS + NT;
    unsigned int* flags = (unsigned int*)(preQ + NT);
    unsigned int* counter = flags + NT;

    // zero flags + counter (doubles only read after their flag is nonzero)
    hipMemsetAsync(flags, 0, (size_t)NT * sizeof(unsigned int) + sizeof(unsigned int),
                   stream);

    dim3 grid(NT), block(256);
    cln_fused<<<grid, block, 0, stream>>>(in, gamma, beta, out, K, tilesPerBatch,
                                          aggS, aggQ, preS, preQ, flags, counter);
}

// Round 4
// 68.553 us; speedup vs baseline: 7.0356x; 7.0356x over previous
//
#include <hip/hip_runtime.h>
#include <math.h>

// CumulativeLayerNorm [B=8, K=8000, H=512] f32.
// out[b,k,h] = gamma[h]*(x[b,k,h]-mean[b,k])*rsqrt(var[b,k]+1e-8)+beta[h],
// mean/var over prefix inputs[b,:k+1,:].
//
// 4-kernel pipeline (parallel segmented scan, SEG=64 frames):
//  1) k_seg_sums   : per-frame sum/sumsq (f32) + per-segment aggregate (f64)
//  2) k_seg_scan   : per-batch exclusive scan of segment aggregates (8 waves)
//  3) k_frame_stats: within-segment wave scan -> mean/istd per frame
//  4) k_normalize  : elementwise apply, float4 + non-temporal stores
//                    (NT stores keep the 131MB input resident in L3 for the
//                     re-read here and for k1 on the next graph replay)

#define HDIM 512
#define F4H (HDIM / 4)     // 128
#define SEG 64             // frames per segment
#define BATCHES 8

typedef float f32x4 __attribute__((ext_vector_type(4)));

// ------------- Kernel 1: per-frame sums + segment aggregates ------------
__global__ __launch_bounds__(256) void k_seg_sums(
    const float* __restrict__ in, float* __restrict__ ssum,
    float* __restrict__ ssq, double* __restrict__ segS,
    double* __restrict__ segQ, int K, int segsPerBatch)
{
    const int lane = threadIdx.x & 63;
    const int wid  = threadIdx.x >> 6;
    const int segGlobal = blockIdx.x;                 // b*segsPerBatch + seg
    const int b   = segGlobal / segsPerBatch;
    const int seg = segGlobal % segsPerBatch;
    const int k0  = seg * SEG;

    double accS = 0.0, accQ = 0.0;
    #pragma unroll 4
    for (int i = 0; i < SEG / 4; ++i) {               // 16 frames per wave
        const int fk = k0 + wid * (SEG / 4) + i;
        if (fk < K) {
            const float4* p = (const float4*)in + ((size_t)b * K + fk) * F4H;
            float4 a = p[lane];
            float4 c = p[lane + 64];
            float s = (a.x + a.y) + (a.z + a.w) + (c.x + c.y) + (c.z + c.w);
            float q = (a.x * a.x + a.y * a.y) + (a.z * a.z + a.w * a.w)
                    + (c.x * c.x + c.y * c.y) + (c.z * c.z + c.w * c.w);
            #pragma unroll
            for (int off = 32; off >= 1; off >>= 1) {
                s += __shfl_xor(s, off);
                q += __shfl_xor(q, off);
            }
            if (lane == 0) {
                ssum[(size_t)b * K + fk] = s;
                ssq[(size_t)b * K + fk]  = q;
            }
            accS += (double)s;                        // all lanes identical
            accQ += (double)q;
        }
    }
    __shared__ double wS[4], wQ[4];
    if (lane == 0) { wS[wid] = accS; wQ[wid] = accQ; }
    __syncthreads();
    if (threadIdx.x == 0) {
        segS[segGlobal] = wS[0] + wS[1] + wS[2] + wS[3];
        segQ[segGlobal] = wQ[0] + wQ[1] + wQ[2] + wQ[3];
    }
}

// ------------- Kernel 2: per-batch exclusive scan of segments -----------
// One block, 8 waves; wave b scans segsPerBatch aggregates (fp64).
__global__ __launch_bounds__(512) void k_seg_scan(
    const double* __restrict__ segS, const double* __restrict__ segQ,
    double* __restrict__ offS, double* __restrict__ offQ, int segsPerBatch)
{
    const int lane = threadIdx.x & 63;
    const int b = threadIdx.x >> 6;                   // 0..7
    if (b >= BATCHES) return;

    double carryS = 0.0, carryQ = 0.0;
    for (int base = 0; base < segsPerBatch; base += 64) {
        const int sidx = base + lane;
        const bool v = sidx < segsPerBatch;
        double s = v ? segS[(size_t)b * segsPerBatch + sidx] : 0.0;
        double q = v ? segQ[(size_t)b * segsPerBatch + sidx] : 0.0;
        const double sIn = s, qIn = q;
        #pragma unroll
        for (int off = 1; off < 64; off <<= 1) {
            double s2 = __shfl_up(s, off);
            double q2 = __shfl_up(q, off);
            if (lane >= off) { s += s2; q += q2; }
        }
        if (v) {   // exclusive prefix = carry + inclusive - own
            offS[(size_t)b * segsPerBatch + sidx] = carryS + s - sIn;
            offQ[(size_t)b * segsPerBatch + sidx] = carryQ + q - qIn;
        }
        carryS += __shfl(s, 63);
        carryQ += __shfl(q, 63);
    }
}

// ------------- Kernel 3: per-frame stats (one wave per segment) ---------
__global__ __launch_bounds__(256) void k_frame_stats(
    const float* __restrict__ ssum, const float* __restrict__ ssq,
    const double* __restrict__ offS, const double* __restrict__ offQ,
    float* __restrict__ mean, float* __restrict__ istd,
    int K, int segsPerBatch)
{
    const int lane = threadIdx.x & 63;
    const int segGlobal = blockIdx.x * 4 + (threadIdx.x >> 6);
    if (segGlobal >= BATCHES * segsPerBatch) return;
    const int b   = segGlobal / segsPerBatch;
    const int seg = segGlobal % segsPerBatch;
    const int k   = seg * SEG + lane;                 // SEG == 64

    double s = 0.0, q = 0.0;
    if (k < K) {
        s = (double)ssum[(size_t)b * K + k];
        q = (double)ssq[(size_t)b * K + k];
    }
    #pragma unroll
    for (int off = 1; off < 64; off <<= 1) {
        double s2 = __shfl_up(s, off);
        double q2 = __shfl_up(q, off);
        if (lane >= off) { s += s2; q += q2; }
    }
    if (k < K) {
        s += offS[segGlobal];
        q += offQ[segGlobal];
        const double cnt = (double)(k + 1) * (double)HDIM;
        const double m = s / cnt;
        const double var = q / cnt - m * m;
        mean[(size_t)b * K + k] = (float)m;
        istd[(size_t)b * K + k] = (float)(1.0 / sqrt(var + 1e-8));
    }
}

// ------------- Kernel 4: normalize (2 frames per block, NT stores) ------
__global__ __launch_bounds__(256) void k_normalize(
    const float* __restrict__ in, const float* __restrict__ gamma,
    const float* __restrict__ beta, const float* __restrict__ mean,
    const float* __restrict__ istd, float* __restrict__ out, int nframes)
{
    const int t = threadIdx.x;
    const int frame = blockIdx.x * 2 + (t >> 7);
    const int c = t & (F4H - 1);
    if (frame >= nframes) return;

    const float m = mean[frame];
    const float r = istd[frame];
    const float4 g  = ((const float4*)gamma)[c];
    const float4 be = ((const float4*)beta)[c];
    const float4 x  = ((const float4*)in)[(size_t)frame * F4H + c];

    f32x4 o;
    o.x = g.x * ((x.x - m) * r) + be.x;
    o.y = g.y * ((x.y - m) * r) + be.y;
    o.z = g.z * ((x.z - m) * r) + be.z;
    o.w = g.w * ((x.w - m) * r) + be.w;
    __builtin_nontemporal_store(o, (f32x4*)out + (size_t)frame * F4H + c);
}

extern "C" void kernel_launch(void* const* d_in, const int* in_sizes, int n_in,
                              void* d_out, int out_size, void* d_ws, size_t ws_size,
                              hipStream_t stream)
{
    const float* in    = (const float*)d_in[0];
    const float* gamma = (const float*)d_in[1];
    const float* beta  = (const float*)d_in[2];
    float* out = (float*)d_out;

    const int H = in_sizes[1];                  // 512
    const int BK = in_sizes[0] / H;             // B*K
    const int B = BATCHES;
    const int K = BK / B;                       // 8000
    const int segsPerBatch = (K + SEG - 1) / SEG;   // 125
    const int NSEG = B * segsPerBatch;              // 1000
    (void)H; (void)n_in; (void)out_size; (void)ws_size;

    // ws layout: ssum/ssq/mean/istd f32 [BK] then segS/segQ/offS/offQ f64 [NSEG]
    float* ssum = (float*)d_ws;
    float* ssq  = ssum + BK;
    float* mean = ssq + BK;
    float* istd = mean + BK;
    double* segS = (double*)(istd + BK);
    double* segQ = segS + NSEG;
    double* offS = segQ + NSEG;
    double* offQ = offS + NSEG;

    k_seg_sums<<<dim3(NSEG), dim3(256), 0, stream>>>(
        in, ssum, ssq, segS, segQ, K, segsPerBatch);
    k_seg_scan<<<dim3(1), dim3(512), 0, stream>>>(
        segS, segQ, offS, offQ, segsPerBatch);
    k_frame_stats<<<dim3((NSEG + 3) / 4), dim3(256), 0, stream>>>(
        ssum, ssq, offS, offQ, mean, istd, K, segsPerBatch);
    k_normalize<<<dim3((BK + 1) / 2), dim3(256), 0, stream>>>(
        in, gamma, beta, mean, istd, out, BK);
}